// Round 13
// baseline (322.022 us; speedup 1.0000x reference)
//
#include <hip/hip_runtime.h>
#include <math.h>

// ---------------------------------------------------------------------------
// SGCN forward — CSR pull aggregation + MFMA dense layers.
//
// R17: MEASUREMENT ROUND. Three consecutive nulls (R14->R16: 264.9, 264.4,
// 262.6) and a ~70us gap between the non-agg budget (floors ~105us) and the
// observed non-agg wall time (~173us). The top-5 profiler window is
// saturated by agg_k instances, so the slow dispatch is invisible. scatter_k
// and gemm1 are idempotent => launching each 3x adds exactly 2*(S+G1) to
// dur_us: total ~329 => floors right, attack mega/gaps next; total ~380-440
// => gemm/scatter is the hog, rebuild it next. Kernels byte-identical to R16
// (best 262.6); only the launcher repeats dispatches.
// ---------------------------------------------------------------------------

typedef _Float16 h4 __attribute__((ext_vector_type(4)));
typedef _Float16 h8 __attribute__((ext_vector_type(8)));
typedef float f32x4 __attribute__((ext_vector_type(4)));

__device__ inline h8 shflx8(h8 v, int m) {
    int4 i = __builtin_bit_cast(int4, v);
    i.x = __shfl_xor(i.x, m);
    i.y = __shfl_xor(i.y, m);
    i.z = __shfl_xor(i.z, m);
    i.w = __shfl_xor(i.w, m);
    return __builtin_bit_cast(h8, i);
}

__device__ inline float fast_tanh(float v) {
    float e = __expf(2.0f * v);
    return 1.0f - 2.0f / (e + 1.0f);
}

// ------------------------------- CSR build ---------------------------------

#define BSHIFT 9
#define BSIZE  512
#define NBMAX  512
#define NREP   8
#define RCAP   1024
#define CAP    (NREP * RCAP)
#define MAXPER 4992

__device__ inline float b1map(const float* W1p, const float* W1n, int k, int c)
{
    if (c < 32) {
        if (k < 64)   return W1p[k * 32 + c];
        if (k >= 128) return W1p[(k - 64) * 32 + c];
        return 0.0f;
    } else {
        int cn = c - 32;
        if (k >= 64)  return W1n[(k - 64) * 32 + cn];
        return 0.0f;
    }
}

__device__ inline float b2map(const float* W2p, const float* W2n, int k, int c)
{
    if (c < 32) {
        if (k < 32)               return W2p[k * 32 + c];
        if (k >= 96 && k < 128)   return W2p[(k - 96 + 32) * 32 + c];
        if (k >= 128 && k < 160)  return W2p[(k - 128 + 64) * 32 + c];
        return 0.0f;
    } else {
        int cn = c - 32;
        if (k >= 32 && k < 64)    return W2n[(k - 32) * 32 + cn];
        if (k >= 64 && k < 96)    return W2n[(k - 64 + 32) * 32 + cn];
        if (k >= 160)             return W2n[(k - 160 + 64) * 32 + cn];
        return 0.0f;
    }
}

__global__ void __launch_bounds__(256) mega_k(
    const int* __restrict__ pos, const int* __restrict__ neg,
    int* __restrict__ pcntR, unsigned* __restrict__ ebuf,
    int E, int n, int nb, int bblocks,
    const float4* __restrict__ x, h4* __restrict__ xh, int n4, int cvtBlocks,
    const float* __restrict__ W1p, const float* __restrict__ W1n,
    const float* __restrict__ W2p, const float* __restrict__ W2n,
    _Float16* __restrict__ Bpack)
{
    int tid = threadIdx.x;
    int bid = blockIdx.x;

    if (bid >= bblocks) {
        int cb = bid - bblocks;
        if (cb < cvtBlocks) {
            int gs = cvtBlocks * 256;
            for (int i = cb * 256 + tid; i < n4; i += gs) {
                float4 v = x[i];
                h4 o = { (_Float16)v.x, (_Float16)v.y, (_Float16)v.z, (_Float16)v.w };
                xh[i] = o;
            }
        } else {
            int slot = (cb - cvtBlocks) * 256 + tid;
            if (slot < 2 * 24 * 64) {
                int mat  = slot / (24 * 64);
                int rem  = slot % (24 * 64);
                int fg   = rem / 64;
                int lane = rem % 64;
                int kk = fg >> 2, nt = fg & 3;
                int g = lane >> 4, m = lane & 15;
                _Float16* dst = Bpack + (size_t)slot * 8;
                int c = nt * 16 + m;
                #pragma unroll
                for (int j = 0; j < 8; ++j) {
                    int k = kk * 32 + g * 8 + j;
                    float v = mat ? b2map(W2p, W2n, k, c) : b1map(W1p, W1n, k, c);
                    dst[j] = (_Float16)v;
                }
            }
        }
        return;
    }

    __shared__ int cnt[NBMAX], gbase[NBMAX], lofs[NBMAX], sc2[256];
    __shared__ unsigned erec[MAXPER], sorted[MAXPER];
    __shared__ unsigned short ep[MAXPER], pd[MAXPER];
    int rep = bid & (NREP - 1);
    int per = (2 * E + bblocks - 1) / bblocks;
    int e0 = bid * per;
    int e1 = min(e0 + per, 2 * E);
    int cntloc = e1 - e0;

    for (int i = tid; i < nb; i += 256) cnt[i] = 0;
    __syncthreads();

    for (int e = e0 + tid; e < e1; e += 256) {
        int nd, sr;
        if (e < E) { nd = pos[E + e];                 sr = pos[e]; }
        else       { int ee = e - E; nd = n + neg[E + ee]; sr = neg[ee]; }
        int p = nd >> BSHIFT;
        int li = e - e0;
        erec[li] = ((unsigned)(nd & (BSIZE - 1)) << 17) | (unsigned)sr;
        ep[li] = (unsigned short)p;
        atomicAdd(&cnt[p], 1);
    }
    __syncthreads();
    for (int i = tid; i < nb; i += 256) {
        int c = cnt[i];
        gbase[i] = c ? atomicAdd(&pcntR[rep * NBMAX + i], c) : 0;
    }
    {
        int a0 = (2 * tid     < nb) ? cnt[2 * tid]     : 0;
        int a1 = (2 * tid + 1 < nb) ? cnt[2 * tid + 1] : 0;
        int s = a0 + a1;
        sc2[tid] = s;
        __syncthreads();
        for (int off = 1; off < 256; off <<= 1) {
            int t = (tid >= off) ? sc2[tid - off] : 0;
            __syncthreads();
            sc2[tid] += t;
            __syncthreads();
        }
        int excl = sc2[tid] - s;
        if (2 * tid     < nb) lofs[2 * tid]     = excl;
        if (2 * tid + 1 < nb) lofs[2 * tid + 1] = excl + a0;
    }
    __syncthreads();
    for (int i = tid; i < nb; i += 256) cnt[i] = 0;
    __syncthreads();
    for (int li = tid; li < cntloc; li += 256) {
        int p = ep[li];
        int r = atomicAdd(&cnt[p], 1);
        int idx = lofs[p] + r;
        sorted[idx] = erec[li];
        pd[idx] = (unsigned short)p;
    }
    __syncthreads();
    for (int t = tid; t < cntloc; t += 256) {
        int p = pd[t];
        int g = gbase[p] + (t - lofs[p]);
        if (g < RCAP)
            ebuf[(size_t)p * CAP + rep * RCAP + g] = sorted[t];
    }
}

__global__ void __launch_bounds__(1024) scatter_k(
    const unsigned* __restrict__ ebuf, const int* __restrict__ pcntR,
    int* __restrict__ cur, int* __restrict__ col, int n, int nb)
{
    __shared__ int lcnt[BSIZE], lbase[BSIZE], sc[256], bb[NBMAX], crp[NREP];
    __shared__ int lcol[CAP];
    int p = blockIdx.x;
    int tid = threadIdx.x;
    int n2 = 2 * n;
    int lo = p << BSHIFT;
    int nn = min(BSIZE, n2 - lo);
    const unsigned* bbuf = ebuf + (size_t)p * CAP;

    if (tid < NREP) crp[tid] = min(pcntR[tid * NBMAX + p], RCAP);

    {
        int a0 = 0, a1 = 0, s = 0;
        if (tid < 256) {
            #pragma unroll
            for (int r = 0; r < NREP; ++r) {
                if (2 * tid     < nb) a0 += min(pcntR[r * NBMAX + 2 * tid],     RCAP);
                if (2 * tid + 1 < nb) a1 += min(pcntR[r * NBMAX + 2 * tid + 1], RCAP);
            }
            s = a0 + a1;
            sc[tid] = s;
        }
        __syncthreads();
        for (int off = 1; off < 256; off <<= 1) {
            int t = (tid < 256 && tid >= off) ? sc[tid - off] : 0;
            __syncthreads();
            if (tid < 256) sc[tid] += t;
            __syncthreads();
        }
        if (tid < 256) {
            int excl = sc[tid] - s;
            bb[2 * tid]     = excl;
            bb[2 * tid + 1] = excl + a0;
        }
    }

    for (int i = tid; i < BSIZE; i += 1024) lcnt[i] = 0;
    __syncthreads();
    int cnttot = crp[0] + crp[1] + crp[2] + crp[3] +
                 crp[4] + crp[5] + crp[6] + crp[7];
    #pragma unroll
    for (int r = 0; r < NREP; ++r) {
        int c = crp[r];
        const unsigned* buf = bbuf + r * RCAP;
        for (int i = tid; i < c; i += 1024)
            atomicAdd(&lcnt[buf[i] >> 17], 1);
    }
    __syncthreads();
    {
        int a0 = 0, a1 = 0, s = 0;
        if (tid < 256) {
            a0 = lcnt[2 * tid]; a1 = lcnt[2 * tid + 1];
            s = a0 + a1;
            sc[tid] = s;
        }
        __syncthreads();
        for (int off = 1; off < 256; off <<= 1) {
            int t = (tid < 256 && tid >= off) ? sc[tid - off] : 0;
            __syncthreads();
            if (tid < 256) sc[tid] += t;
            __syncthreads();
        }
        if (tid < 256) {
            int excl = sc[tid] - s;
            lbase[2 * tid]     = excl;
            lbase[2 * tid + 1] = excl + a0;
        }
    }
    __syncthreads();
    int gb = bb[p];
    for (int i = tid; i < nn; i += 1024)
        cur[lo + i] = gb + lbase[i] + lcnt[i];
    __syncthreads();
    #pragma unroll
    for (int r = 0; r < NREP; ++r) {
        int c = crp[r];
        const unsigned* buf = bbuf + r * RCAP;
        for (int i = tid; i < c; i += 1024) {
            unsigned v = buf[i];
            int slot = atomicAdd(&lbase[v >> 17], 1);
            lcol[slot] = (int)(v & 0x1FFFFu);
        }
    }
    __syncthreads();
    for (int t = tid; t < cnttot; t += 1024)
        col[gb + t] = lcol[t];
}

// ------------------------------- aggregation -------------------------------

__global__ void __launch_bounds__(256) agg_k(
    const h8* __restrict__ feat8,
    const int* __restrict__ cur, const int* __restrict__ col,
    h8* __restrict__ ag8, int n)
{
    int tid = threadIdx.x;
    int wave = tid >> 6, lane = tid & 63;
    int s = lane >> 2, f = lane & 3;
    int list = s >> 3;
    int sub = s & 7;

    int stride = gridDim.x * 4;
    for (int node = blockIdx.x * 4 + wave; node < n; node += stride) {
        int idx = list ? n + node : node;
        int r0 = idx ? cur[idx - 1] : 0;
        int r1 = cur[idx];

        h8 acc0 = {}, acc1 = {};
        #pragma unroll 2
        for (int it = r0 + sub; it < r1; it += 8) {
            unsigned srcb = (unsigned)col[it] * 8;
            acc0 = acc0 + feat8[srcb + f];
            acc1 = acc1 + feat8[srcb + 4 + f];
        }
        acc0 = acc0 + shflx8(acc0, 4);
        acc1 = acc1 + shflx8(acc1, 4);
        acc0 = acc0 + shflx8(acc0, 8);
        acc1 = acc1 + shflx8(acc1, 8);
        acc0 = acc0 + shflx8(acc0, 16);
        acc1 = acc1 + shflx8(acc1, 16);
        _Float16 inv = (_Float16)(1.0f / (float)max(r1 - r0, 1));
        h8 iv = { inv, inv, inv, inv, inv, inv, inv, inv };
        if (sub == 0) {
            ag8[(unsigned)(node * 16 + list * 8 + f)]     = acc0 * iv;
            ag8[(unsigned)(node * 16 + list * 8 + 4 + f)] = acc1 * iv;
        }
    }
}

// --------------------------------- GEMM ------------------------------------

#define ROWP 200

__device__ inline int nmap(int g, int r) {
    return 32 * (16 * (g >> 3) + (r >> 2)) + 4 * (g & 7) + (r & 3);
}

__global__ void __launch_bounds__(256) gemm_k(
    const h8* __restrict__ ag8, const h8* __restrict__ feat8,
    const h8* __restrict__ Bp,
    const float* __restrict__ bp, const float* __restrict__ bn,
    float* __restrict__ outf, _Float16* __restrict__ outh,
    int f32out, int n)
{
    __shared__ _Float16 A_lds[64 * ROWP];
    int tid = threadIdx.x;
    int bid = blockIdx.x;

    for (int ch = tid; ch < 64 * 24; ch += 256) {
        int r = ch / 24, p = ch % 24;
        int row = min(nmap(bid, r), n - 1);
        h8 v = (p < 16) ? ag8[(size_t)row * 16 + p]
                        : feat8[(size_t)row * 8 + (p - 16)];
        *(h8*)&A_lds[r * ROWP + p * 8] = v;
    }
    __syncthreads();

    int w = tid >> 6, lane = tid & 63;
    int m = lane & 15, g = lane >> 4;

    h8 a[6];
    #pragma unroll
    for (int kk = 0; kk < 6; ++kk)
        a[kk] = *(const h8*)&A_lds[(w * 16 + m) * ROWP + kk * 32 + g * 8];

    #pragma unroll
    for (int nt = 0; nt < 4; ++nt) {
        f32x4 acc = { 0.f, 0.f, 0.f, 0.f };
        #pragma unroll
        for (int kk = 0; kk < 6; ++kk) {
            h8 b = Bp[(kk * 4 + nt) * 64 + lane];
            acc = __builtin_amdgcn_mfma_f32_16x16x32_f16(a[kk], b, acc, 0, 0, 0);
        }
        int colc = nt * 16 + m;
        float bias = (colc < 32) ? bp[colc] : bn[colc - 32];
        #pragma unroll
        for (int reg = 0; reg < 4; ++reg) {
            int node = nmap(bid, w * 16 + g * 4 + reg);
            if (node < n) {
                float val = fast_tanh(acc[reg] + bias);
                if (f32out) outf[(size_t)node * 64 + colc] = val;
                else        outh[(size_t)node * 64 + colc] = (_Float16)val;
            }
        }
    }
}

extern "C" void kernel_launch(void* const* d_in, const int* in_sizes, int n_in,
                              void* d_out, int out_size, void* d_ws, size_t ws_size,
                              hipStream_t stream)
{
    const float* x   = (const float*)d_in[0];
    const float* W1p = (const float*)d_in[1];
    const float* b1p = (const float*)d_in[2];
    const float* W1n = (const float*)d_in[3];
    const float* b1n = (const float*)d_in[4];
    const float* W2p = (const float*)d_in[5];
    const float* b2p = (const float*)d_in[6];
    const float* W2n = (const float*)d_in[7];
    const float* b2n = (const float*)d_in[8];
    const int*   pos = (const int*)d_in[9];
    const int*   neg = (const int*)d_in[10];

    int n = in_sizes[0] / 64;       // 100000
    int E = in_sizes[9] / 2;        // 1250000
    int n2 = 2 * n;
    int nb = (n2 + BSIZE - 1) / BSIZE;   // 391 buckets

    int*      pcntR = (int*)d_ws;
    int*      cur   = pcntR + NREP * NBMAX;
    int*      col   = cur + n2;
    _Float16* Bpack = (_Float16*)(col + 2 * (size_t)E);
    _Float16* xh    = Bpack + 2 * 24 * 64 * 8;
    unsigned* ebuf  = (unsigned*)(xh + (size_t)n * 64);
    _Float16* zh    = (_Float16*)ebuf;            // aliases ebuf (dead after scatter)
    h8*       ag8   = (h8*)d_out;

    hipMemsetAsync(pcntR, 0, NREP * NBMAX * sizeof(int), stream);

    int bblocks = 512;
    int n4 = n * 16;
    int cvtBlocks = 512;

    mega_k<<<bblocks + cvtBlocks + 12, 256, 0, stream>>>(
        pos, neg, pcntR, ebuf, E, n, nb, bblocks,
        (const float4*)x, (h4*)xh, n4, cvtBlocks,
        W1p, W1n, W2p, W2n, Bpack);

    // PROBE: scatter_k is idempotent — run 3x. Delta_total includes 2*S.
    scatter_k<<<nb, 1024, 0, stream>>>(ebuf, pcntR, cur, col, n, nb);
    scatter_k<<<nb, 1024, 0, stream>>>(ebuf, pcntR, cur, col, n, nb);
    scatter_k<<<nb, 1024, 0, stream>>>(ebuf, pcntR, cur, col, n, nb);

    int ablocks = 2048;
    int gblocks = (n + 63) / 64 + 5;   // 1568: covers the bijective node map

    // layer 1: agg(x) -> ag ; gemm1 idempotent — run 3x. Delta includes 2*G1.
    agg_k <<<ablocks, 256, 0, stream>>>((const h8*)xh, cur, col, ag8, n);
    gemm_k<<<gblocks, 256, 0, stream>>>(ag8, (const h8*)xh, (const h8*)Bpack,
                                        b1p, b1n, nullptr, zh, 0, n);
    gemm_k<<<gblocks, 256, 0, stream>>>(ag8, (const h8*)xh, (const h8*)Bpack,
                                        b1p, b1n, nullptr, zh, 0, n);
    gemm_k<<<gblocks, 256, 0, stream>>>(ag8, (const h8*)xh, (const h8*)Bpack,
                                        b1p, b1n, nullptr, zh, 0, n);

    // layer 2: agg(z) -> ag ; gemm(A2=[Mp|Mn|z]) -> out (fp32)
    agg_k <<<ablocks, 256, 0, stream>>>((const h8*)zh, cur, col, ag8, n);
    gemm_k<<<gblocks, 256, 0, stream>>>(ag8, (const h8*)zh,
                                        (const h8*)(Bpack + 24 * 64 * 8),
                                        b2p, b2n, (float*)d_out, nullptr, 1, n);
}